// Round 5
// baseline (608.885 us; speedup 1.0000x reference)
//
#include <hip/hip_runtime.h>

#define TSTEPS 30
#define KP2 136           // 128 h + 8 pad halfs (272B row stride); gate frags read only k<128
#define LOFF (64 * KP2)   // lo-plane offset (halfs) inside flat HL array

#define LOG2E     1.44269504f
#define TWO_LOG2E 2.88539008f

// R9: XOR element-index bit4 with row bit3 (write-conflict spread). Kept.
#define SWZ(row, e) ((e) ^ ((((row) >> 3) & 1) << 4))

typedef _Float16 half8 __attribute__((ext_vector_type(8)));
typedef _Float16 half4 __attribute__((ext_vector_type(4)));
typedef float f32x4 __attribute__((ext_vector_type(4)));

#if __has_builtin(__builtin_amdgcn_mfma_f32_16x16x16f16)
#define XK16 1
#else
#define XK16 0
#endif

__device__ __forceinline__ float fexp2(float x) { return __builtin_amdgcn_exp2f(x); }
__device__ __forceinline__ float frcp(float x)  { return __builtin_amdgcn_rcpf(x); }
__device__ __forceinline__ float fsig_pre(float x)  { return frcp(1.0f + fexp2(-x)); }
__device__ __forceinline__ float ftanh_pre(float x) { return 1.0f - 2.0f * frcp(1.0f + fexp2(x)); }

// R11: 64 rows/block (tiles T0..T3), 8 waves, R3 ordering (552us best).
// R12 anti-phase REVERTED (regressed: HW issue arbiter already interleaves waves;
// it also induced ~10MB scratch). R13 (this round): VALU instruction-count diet.
//  - bias/einit enter as the C operand of the kc=0 MFMA (persistent VGPR f32x4),
//    killing ~32 v_accvgpr_write init moves per phase.
//  - SWZ algebra: bit3(t*16+quad*4+r) == quad>>1 (r,t-independent) and
//    bit3(t*16+col) == col>>3, so ALL h/l writes and frag reads reduce to one
//    per-thread base index + compile-time immediate offsets (hS/lS flattened
//    into HL[2][64][KP2]; lo = +LOFF).
#define CELL_ROW(ACC, CC, T, R) do {                                    \
    const float gi_ = fsig_pre(ACC[0][R]);                              \
    const float gf_ = fsig_pre(ACC[1][R]);                              \
    const float gg_ = ftanh_pre(ACC[2][R]);                             \
    const float go_ = fsig_pre(ACC[3][R]);                              \
    CC = gf_ * CC + gi_ * gg_;                                          \
    const float hv_ = go_ * ftanh_pre(TWO_LOG2E * CC);                  \
    const _Float16 hh_ = (_Float16)hv_;                                 \
    Lp[wbase + ((T) * 16 + (R)) * KP2] = hh_;                           \
    Lp[wbase + LOFF + ((T) * 16 + (R)) * KP2] = (_Float16)(hv_ - (float)hh_); \
} while (0)

__global__ __launch_bounds__(512, 2)
void lstm30_kernel(const float* __restrict__ last_obs_rel,
                   const float* __restrict__ h0,
                   const float* __restrict__ c0,
                   const float* __restrict__ W_sp,
                   const float* __restrict__ b_sp,
                   const float* __restrict__ W_ih,
                   const float* __restrict__ b_ih,
                   const float* __restrict__ W_hh,
                   const float* __restrict__ b_hh,
                   const float* __restrict__ W_out,
                   const float* __restrict__ b_out,
                   float* __restrict__ out)
{
    __shared__ _Float16 HL[2][64][KP2];   // [0]=hi plane, [1]=lo plane
#if XK16
    __shared__ _Float16 xS[4][16][20];
#else
    __shared__ _Float16 xS[4][16][32];
#endif
    _Float16* const Lp = &HL[0][0][0];

    const int tid  = threadIdx.x;
    const int w    = tid >> 6;
    const int L    = tid & 63;
    const int quad = L >> 4;
    const int col  = L & 15;
    const int base = blockIdx.x << 6;   // 64 rows/block

    // ---- gate B fragments: W'[k][G], G = nt*128 + 16w + col, pre-scaled ----
#if XK16
    half8 Wf[4][4];
    half4 Wf4[4];
#else
    half8 Wf[4][5];
#endif
    f32x4 biasv[4];
    #pragma unroll
    for (int nt = 0; nt < 4; ++nt) {
        const int G = nt * 128 + w * 16 + col;
        const float gsc = (nt == 2) ? TWO_LOG2E : LOG2E;
        const float b = (b_ih[G] + b_hh[G]) * gsc;
        biasv[nt] = (f32x4){b, b, b, b};
        #pragma unroll
        for (int kc = 0; kc < 4; ++kc) {
            const int k0 = kc * 32 + quad * 8;
            const float4 a = *(const float4*)&W_hh[G * 128 + k0];
            const float4 bb = *(const float4*)&W_hh[G * 128 + k0 + 4];
            half8 hh;
            hh[0] = (_Float16)(a.x * gsc); hh[1] = (_Float16)(a.y * gsc);
            hh[2] = (_Float16)(a.z * gsc); hh[3] = (_Float16)(a.w * gsc);
            hh[4] = (_Float16)(bb.x * gsc); hh[5] = (_Float16)(bb.y * gsc);
            hh[6] = (_Float16)(bb.z * gsc); hh[7] = (_Float16)(bb.w * gsc);
            Wf[nt][kc] = hh;
        }
#if XK16
        {
            const float4 a = *(const float4*)&W_ih[G * 16 + quad * 4];
            half4 h4;
            h4[0] = (_Float16)(a.x * gsc); h4[1] = (_Float16)(a.y * gsc);
            h4[2] = (_Float16)(a.z * gsc); h4[3] = (_Float16)(a.w * gsc);
            Wf4[nt] = h4;
        }
#else
        {
            const int k0 = 128 + quad * 8;
            float v[8];
            if (k0 < 144) {
                const float4 a = *(const float4*)&W_ih[G * 16 + (k0 - 128)];
                const float4 bb = *(const float4*)&W_ih[G * 16 + (k0 - 128) + 4];
                v[0]=a.x; v[1]=a.y; v[2]=a.z; v[3]=a.w;
                v[4]=bb.x; v[5]=bb.y; v[6]=bb.z; v[7]=bb.w;
            } else {
                #pragma unroll
                for (int jj = 0; jj < 8; ++jj) v[jj] = 0.0f;
            }
            half8 hh;
            #pragma unroll
            for (int jj = 0; jj < 8; ++jj) hh[jj] = (_Float16)(v[jj] * gsc);
            Wf[nt][4] = hh;
        }
#endif
    }

    const float ws0 = W_sp[col * 2 + 0];
    const float ws1 = W_sp[col * 2 + 1];
    const float bs  = b_sp[col];
    const float bo0 = b_out[0], bo1 = b_out[1];

    // ---- every wave holds ONE Ef variant: M-path (w0,1,4,5) or Wout (w2,3,6,7) ----
    half8 Ef[4];
    f32x4 einitv;
    {
        const bool isM = ((w & 2) == 0);
        #pragma unroll
        for (int kc = 0; kc < 4; ++kc) {
            const int k0 = kc * 32 + quad * 8;
            const float4 a0 = *(const float4*)&W_out[k0];
            const float4 a1 = *(const float4*)&W_out[k0 + 4];
            const float4 b0 = *(const float4*)&W_out[128 + k0];
            const float4 b1 = *(const float4*)&W_out[128 + k0 + 4];
            float r0[8] = {a0.x,a0.y,a0.z,a0.w,a1.x,a1.y,a1.z,a1.w};
            float r1[8] = {b0.x,b0.y,b0.z,b0.w,b1.x,b1.y,b1.z,b1.w};
            half8 he;
            #pragma unroll
            for (int jj = 0; jj < 8; ++jj)
                he[jj] = isM ? (_Float16)((ws0 * r0[jj] + ws1 * r1[jj]) * TWO_LOG2E)
                             : (_Float16)((col == 0) ? r0[jj] : (col == 1) ? r1[jj] : 0.0f);
            Ef[kc] = he;
        }
        const float e = isM ? (ws0 * bo0 + ws1 * bo1 + bs) * TWO_LOG2E
                            : ((col == 0) ? bo0 : (col == 1) ? bo1 : 0.0f);
        einitv = (f32x4){e, e, e, e};
    }

    float c[4][4];
    #pragma unroll
    for (int t = 0; t < 4; ++t)
        #pragma unroll
        for (int r = 0; r < 4; ++r)
            c[t][r] = c0[(base + t * 16 + quad * 4 + r) * 128 + w * 16 + col];

    // ---- per-thread LDS base indices (all later accesses are base + imm) ----
    const int j     = w * 16 + col;
    const int wbase = (quad * 4) * KP2 + (j ^ ((quad >> 1) << 4));          // writes
    const int rbase = col * KP2 + ((quad * 8) ^ ((col >> 3) << 4));         // frag reads

    // ---- prologue ----
    for (int idx = tid; idx < 64 * 128; idx += 512) {
        const int r = idx >> 7, kk = idx & 127;
        const float v = h0[base * 128 + idx];
        const _Float16 hi = (_Float16)v;
        Lp[r * KP2 + SWZ(r, kk)] = hi;
        Lp[LOFF + r * KP2 + SWZ(r, kk)] = (_Float16)(v - (float)hi);
    }
    #pragma unroll
    for (int hlf = 0; hlf < 2; ++hlf) {
        const int rr = (tid >> 4) + hlf * 32;
        const float p0 = last_obs_rel[(base + rr) * 2 + 0];
        const float p1 = last_obs_rel[(base + rr) * 2 + 1];
        xS[rr >> 4][rr & 15][tid & 15] = (_Float16)ftanh_pre(TWO_LOG2E * (ws0 * p0 + ws1 * p1 + bs));
    }
#if !XK16
    for (int flat = tid; flat < 4 * 16 * 16; flat += 512) {
        xS[flat >> 8][(flat >> 4) & 15][16 + (flat & 15)] = (_Float16)0.0f;
    }
#endif
    __syncthreads();

    f32x4 accT0[4], accT1[4], accT2[4], accT3[4];

    for (int k = 0; k < TSTEPS; ++k) {
        // ============ EVEN: gates(T0,T2;k) h-part ; finish+cell(T1,T3;k-1) ============
        {
            half8 a0[4], a2[4];
            #pragma unroll
            for (int kc = 0; kc < 4; ++kc) {
                a0[kc] = *(const half8*)&Lp[rbase + kc * 32];
                a2[kc] = *(const half8*)&Lp[rbase + 2 * 2176 + kc * 32];
            }

            if (k > 0) {   // finish gates(T1,T3;k-1): x part
#if XK16
                const half4 x1 = *(const half4*)&xS[1][col][quad * 4];
                const half4 x3 = *(const half4*)&xS[3][col][quad * 4];
                #pragma unroll
                for (int nt = 0; nt < 4; ++nt) {
                    accT1[nt] = __builtin_amdgcn_mfma_f32_16x16x16f16(x1, Wf4[nt], accT1[nt], 0, 0, 0);
                    accT3[nt] = __builtin_amdgcn_mfma_f32_16x16x16f16(x3, Wf4[nt], accT3[nt], 0, 0, 0);
                }
#else
                const half8 x1 = *(const half8*)&xS[1][col][quad * 8];
                const half8 x3 = *(const half8*)&xS[3][col][quad * 8];
                #pragma unroll
                for (int nt = 0; nt < 4; ++nt) {
                    accT1[nt] = __builtin_amdgcn_mfma_f32_16x16x32_f16(x1, Wf[nt][4], accT1[nt], 0, 0, 0);
                    accT3[nt] = __builtin_amdgcn_mfma_f32_16x16x32_f16(x3, Wf[nt][4], accT3[nt], 0, 0, 0);
                }
#endif
            }

            // gates: kc=0 consumes biasv as MFMA-C (no acc init moves)
            #pragma unroll
            for (int nt = 0; nt < 4; ++nt) {
                accT0[nt] = __builtin_amdgcn_mfma_f32_16x16x32_f16(a0[0], Wf[nt][0], biasv[nt], 0, 0, 0);
                accT2[nt] = __builtin_amdgcn_mfma_f32_16x16x32_f16(a2[0], Wf[nt][0], biasv[nt], 0, 0, 0);
            }
            #pragma unroll
            for (int kc = 1; kc < 4; ++kc)
                #pragma unroll
                for (int nt = 0; nt < 4; ++nt) {
                    accT0[nt] = __builtin_amdgcn_mfma_f32_16x16x32_f16(a0[kc], Wf[nt][kc], accT0[nt], 0, 0, 0);
                    accT2[nt] = __builtin_amdgcn_mfma_f32_16x16x32_f16(a2[kc], Wf[nt][kc], accT2[nt], 0, 0, 0);
                }

            if (k > 0) {   // cell(T1,T3;k-1) rows 0-1 — VALU overlaps MFMA drain
                #pragma unroll
                for (int r = 0; r < 2; ++r) {
                    CELL_ROW(accT1, c[1][r], 1, r);
                    CELL_ROW(accT3, c[3][r], 3, r);
                }
            }

            f32x4 eacc;
            if (k > 0 && w == 0) {        // x(T0): hi only
                eacc = __builtin_amdgcn_mfma_f32_16x16x32_f16(a0[0], Ef[0], einitv, 0, 0, 0);
                #pragma unroll
                for (int kc = 1; kc < 4; ++kc)
                    eacc = __builtin_amdgcn_mfma_f32_16x16x32_f16(a0[kc], Ef[kc], eacc, 0, 0, 0);
            }
            if (k > 0 && w == 1) {        // x(T2): hi only
                eacc = __builtin_amdgcn_mfma_f32_16x16x32_f16(a2[0], Ef[0], einitv, 0, 0, 0);
                #pragma unroll
                for (int kc = 1; kc < 4; ++kc)
                    eacc = __builtin_amdgcn_mfma_f32_16x16x32_f16(a2[kc], Ef[kc], eacc, 0, 0, 0);
            }
            if (k > 0 && w == 2) {        // rel(T0): hi + lo
                eacc = __builtin_amdgcn_mfma_f32_16x16x32_f16(a0[0], Ef[0], einitv, 0, 0, 0);
                #pragma unroll
                for (int kc = 1; kc < 4; ++kc)
                    eacc = __builtin_amdgcn_mfma_f32_16x16x32_f16(a0[kc], Ef[kc], eacc, 0, 0, 0);
                #pragma unroll
                for (int kc = 0; kc < 4; ++kc) {
                    const half8 aL = *(const half8*)&Lp[rbase + LOFF + kc * 32];
                    eacc = __builtin_amdgcn_mfma_f32_16x16x32_f16(aL, Ef[kc], eacc, 0, 0, 0);
                }
            }
            if (k > 0 && w == 3) {        // rel(T2): hi + lo
                eacc = __builtin_amdgcn_mfma_f32_16x16x32_f16(a2[0], Ef[0], einitv, 0, 0, 0);
                #pragma unroll
                for (int kc = 1; kc < 4; ++kc)
                    eacc = __builtin_amdgcn_mfma_f32_16x16x32_f16(a2[kc], Ef[kc], eacc, 0, 0, 0);
                #pragma unroll
                for (int kc = 0; kc < 4; ++kc) {
                    const half8 aL = *(const half8*)&Lp[rbase + 2 * 2176 + LOFF + kc * 32];
                    eacc = __builtin_amdgcn_mfma_f32_16x16x32_f16(aL, Ef[kc], eacc, 0, 0, 0);
                }
            }

            if (k > 0) {   // cell(T1,T3;k-1) rows 2-3
                #pragma unroll
                for (int r = 2; r < 4; ++r) {
                    CELL_ROW(accT1, c[1][r], 1, r);
                    CELL_ROW(accT3, c[3][r], 3, r);
                }
            }

            if (k > 0 && w == 0) {   // x_k(T0); k=0 keeps obs-x0
                #pragma unroll
                for (int r = 0; r < 4; ++r)
                    xS[0][quad * 4 + r][col] = (_Float16)ftanh_pre(eacc[r]);
            }
            if (k > 0 && w == 1) {   // x_k(T2)
                #pragma unroll
                for (int r = 0; r < 4; ++r)
                    xS[2][quad * 4 + r][col] = (_Float16)ftanh_pre(eacc[r]);
            }
            if (k > 0 && w == 2 && col < 2) {   // rel_{k-1}(T0)
                #pragma unroll
                for (int r = 0; r < 4; ++r)
                    out[(base + quad * 4 + r) * (TSTEPS * 2) + (k - 1) * 2 + col] = eacc[r];
            }
            if (k > 0 && w == 3 && col < 2) {   // rel_{k-1}(T2)
                #pragma unroll
                for (int r = 0; r < 4; ++r)
                    out[(base + 32 + quad * 4 + r) * (TSTEPS * 2) + (k - 1) * 2 + col] = eacc[r];
            }
            __syncthreads();
        }
        // ============ ODD: gates(T1,T3;k) h-part ; finish+cell(T0,T2;k) ============
        {
            half8 a1[4], a3[4];
            #pragma unroll
            for (int kc = 0; kc < 4; ++kc) {
                a1[kc] = *(const half8*)&Lp[rbase + 2176 + kc * 32];
                a3[kc] = *(const half8*)&Lp[rbase + 3 * 2176 + kc * 32];
            }

            {   // finish gates(T0,T2;k): x part (xS = obs-x0 at k=0)
#if XK16
                const half4 x0 = *(const half4*)&xS[0][col][quad * 4];
                const half4 x2 = *(const half4*)&xS[2][col][quad * 4];
                #pragma unroll
                for (int nt = 0; nt < 4; ++nt) {
                    accT0[nt] = __builtin_amdgcn_mfma_f32_16x16x16f16(x0, Wf4[nt], accT0[nt], 0, 0, 0);
                    accT2[nt] = __builtin_amdgcn_mfma_f32_16x16x16f16(x2, Wf4[nt], accT2[nt], 0, 0, 0);
                }
#else
                const half8 x0 = *(const half8*)&xS[0][col][quad * 8];
                const half8 x2 = *(const half8*)&xS[2][col][quad * 8];
                #pragma unroll
                for (int nt = 0; nt < 4; ++nt) {
                    accT0[nt] = __builtin_amdgcn_mfma_f32_16x16x32_f16(x0, Wf[nt][4], accT0[nt], 0, 0, 0);
                    accT2[nt] = __builtin_amdgcn_mfma_f32_16x16x32_f16(x2, Wf[nt][4], accT2[nt], 0, 0, 0);
                }
#endif
            }

            #pragma unroll
            for (int nt = 0; nt < 4; ++nt) {
                accT1[nt] = __builtin_amdgcn_mfma_f32_16x16x32_f16(a1[0], Wf[nt][0], biasv[nt], 0, 0, 0);
                accT3[nt] = __builtin_amdgcn_mfma_f32_16x16x32_f16(a3[0], Wf[nt][0], biasv[nt], 0, 0, 0);
            }
            #pragma unroll
            for (int kc = 1; kc < 4; ++kc)
                #pragma unroll
                for (int nt = 0; nt < 4; ++nt) {
                    accT1[nt] = __builtin_amdgcn_mfma_f32_16x16x32_f16(a1[kc], Wf[nt][kc], accT1[nt], 0, 0, 0);
                    accT3[nt] = __builtin_amdgcn_mfma_f32_16x16x32_f16(a3[kc], Wf[nt][kc], accT3[nt], 0, 0, 0);
                }

            {   // cell(T0,T2;k) rows 0-1
                #pragma unroll
                for (int r = 0; r < 2; ++r) {
                    CELL_ROW(accT0, c[0][r], 0, r);
                    CELL_ROW(accT2, c[2][r], 2, r);
                }
            }

            f32x4 eacc;
            if (w == 4) {        // x(T1): hi only
                eacc = __builtin_amdgcn_mfma_f32_16x16x32_f16(a1[0], Ef[0], einitv, 0, 0, 0);
                #pragma unroll
                for (int kc = 1; kc < 4; ++kc)
                    eacc = __builtin_amdgcn_mfma_f32_16x16x32_f16(a1[kc], Ef[kc], eacc, 0, 0, 0);
            }
            if (w == 5) {        // x(T3): hi only
                eacc = __builtin_amdgcn_mfma_f32_16x16x32_f16(a3[0], Ef[0], einitv, 0, 0, 0);
                #pragma unroll
                for (int kc = 1; kc < 4; ++kc)
                    eacc = __builtin_amdgcn_mfma_f32_16x16x32_f16(a3[kc], Ef[kc], eacc, 0, 0, 0);
            }
            if (w == 6) {        // rel(T1): hi + lo
                eacc = __builtin_amdgcn_mfma_f32_16x16x32_f16(a1[0], Ef[0], einitv, 0, 0, 0);
                #pragma unroll
                for (int kc = 1; kc < 4; ++kc)
                    eacc = __builtin_amdgcn_mfma_f32_16x16x32_f16(a1[kc], Ef[kc], eacc, 0, 0, 0);
                #pragma unroll
                for (int kc = 0; kc < 4; ++kc) {
                    const half8 aL = *(const half8*)&Lp[rbase + 2176 + LOFF + kc * 32];
                    eacc = __builtin_amdgcn_mfma_f32_16x16x32_f16(aL, Ef[kc], eacc, 0, 0, 0);
                }
            }
            if (w == 7) {        // rel(T3): hi + lo
                eacc = __builtin_amdgcn_mfma_f32_16x16x32_f16(a3[0], Ef[0], einitv, 0, 0, 0);
                #pragma unroll
                for (int kc = 1; kc < 4; ++kc)
                    eacc = __builtin_amdgcn_mfma_f32_16x16x32_f16(a3[kc], Ef[kc], eacc, 0, 0, 0);
                #pragma unroll
                for (int kc = 0; kc < 4; ++kc) {
                    const half8 aL = *(const half8*)&Lp[rbase + 3 * 2176 + LOFF + kc * 32];
                    eacc = __builtin_amdgcn_mfma_f32_16x16x32_f16(aL, Ef[kc], eacc, 0, 0, 0);
                }
            }

            {   // cell(T0,T2;k) rows 2-3
                #pragma unroll
                for (int r = 2; r < 4; ++r) {
                    CELL_ROW(accT0, c[0][r], 0, r);
                    CELL_ROW(accT2, c[2][r], 2, r);
                }
            }

            if (k > 0 && w == 4) {   // x_k(T1); k=0 keeps obs-x0
                #pragma unroll
                for (int r = 0; r < 4; ++r)
                    xS[1][quad * 4 + r][col] = (_Float16)ftanh_pre(eacc[r]);
            }
            if (k > 0 && w == 5) {   // x_k(T3)
                #pragma unroll
                for (int r = 0; r < 4; ++r)
                    xS[3][quad * 4 + r][col] = (_Float16)ftanh_pre(eacc[r]);
            }
            if (k > 0 && w == 6 && col < 2) {   // rel_{k-1}(T1)
                #pragma unroll
                for (int r = 0; r < 4; ++r)
                    out[(base + 16 + quad * 4 + r) * (TSTEPS * 2) + (k - 1) * 2 + col] = eacc[r];
            }
            if (k > 0 && w == 7 && col < 2) {   // rel_{k-1}(T3)
                #pragma unroll
                for (int r = 0; r < 4; ++r)
                    out[(base + 48 + quad * 4 + r) * (TSTEPS * 2) + (k - 1) * 2 + col] = eacc[r];
            }
            __syncthreads();
        }
    }

    // ============ epilogue: finish T1/T3 step 29; rel_29 all four tiles ============
    {
        {   // finish gates(T1,T3;29): x part
#if XK16
            const half4 x1 = *(const half4*)&xS[1][col][quad * 4];
            const half4 x3 = *(const half4*)&xS[3][col][quad * 4];
            #pragma unroll
            for (int nt = 0; nt < 4; ++nt) {
                accT1[nt] = __builtin_amdgcn_mfma_f32_16x16x16f16(x1, Wf4[nt], accT1[nt], 0, 0, 0);
                accT3[nt] = __builtin_amdgcn_mfma_f32_16x16x16f16(x3, Wf4[nt], accT3[nt], 0, 0, 0);
            }
#else
            const half8 x1 = *(const half8*)&xS[1][col][quad * 8];
            const half8 x3 = *(const half8*)&xS[3][col][quad * 8];
            #pragma unroll
            for (int nt = 0; nt < 4; ++nt) {
                accT1[nt] = __builtin_amdgcn_mfma_f32_16x16x32_f16(x1, Wf[nt][4], accT1[nt], 0, 0, 0);
                accT3[nt] = __builtin_amdgcn_mfma_f32_16x16x32_f16(x3, Wf[nt][4], accT3[nt], 0, 0, 0);
            }
#endif
        }
        if (w == 2) {   // rel_29(T0) from h_30(T0)
            f32x4 eacc = __builtin_amdgcn_mfma_f32_16x16x32_f16(
                *(const half8*)&Lp[rbase + 0], Ef[0], einitv, 0, 0, 0);
            #pragma unroll
            for (int kc = 1; kc < 4; ++kc)
                eacc = __builtin_amdgcn_mfma_f32_16x16x32_f16(
                    *(const half8*)&Lp[rbase + kc * 32], Ef[kc], eacc, 0, 0, 0);
            #pragma unroll
            for (int kc = 0; kc < 4; ++kc)
                eacc = __builtin_amdgcn_mfma_f32_16x16x32_f16(
                    *(const half8*)&Lp[rbase + LOFF + kc * 32], Ef[kc], eacc, 0, 0, 0);
            if (col < 2) {
                #pragma unroll
                for (int r = 0; r < 4; ++r)
                    out[(base + quad * 4 + r) * (TSTEPS * 2) + (TSTEPS - 1) * 2 + col] = eacc[r];
            }
        }
        if (w == 3) {   // rel_29(T2) from h_30(T2)
            f32x4 eacc = __builtin_amdgcn_mfma_f32_16x16x32_f16(
                *(const half8*)&Lp[rbase + 2 * 2176], Ef[0], einitv, 0, 0, 0);
            #pragma unroll
            for (int kc = 1; kc < 4; ++kc)
                eacc = __builtin_amdgcn_mfma_f32_16x16x32_f16(
                    *(const half8*)&Lp[rbase + 2 * 2176 + kc * 32], Ef[kc], eacc, 0, 0, 0);
            #pragma unroll
            for (int kc = 0; kc < 4; ++kc)
                eacc = __builtin_amdgcn_mfma_f32_16x16x32_f16(
                    *(const half8*)&Lp[rbase + 2 * 2176 + LOFF + kc * 32], Ef[kc], eacc, 0, 0, 0);
            if (col < 2) {
                #pragma unroll
                for (int r = 0; r < 4; ++r)
                    out[(base + 32 + quad * 4 + r) * (TSTEPS * 2) + (TSTEPS - 1) * 2 + col] = eacc[r];
            }
        }
        #pragma unroll
        for (int r = 0; r < 4; ++r) {   // cell(T1,T3;29) -> h_30
            CELL_ROW(accT1, c[1][r], 1, r);
            CELL_ROW(accT3, c[3][r], 3, r);
        }
        __syncthreads();
        if (w == 6) {   // rel_29(T1) from h_30(T1)
            f32x4 eacc = __builtin_amdgcn_mfma_f32_16x16x32_f16(
                *(const half8*)&Lp[rbase + 2176], Ef[0], einitv, 0, 0, 0);
            #pragma unroll
            for (int kc = 1; kc < 4; ++kc)
                eacc = __builtin_amdgcn_mfma_f32_16x16x32_f16(
                    *(const half8*)&Lp[rbase + 2176 + kc * 32], Ef[kc], eacc, 0, 0, 0);
            #pragma unroll
            for (int kc = 0; kc < 4; ++kc)
                eacc = __builtin_amdgcn_mfma_f32_16x16x32_f16(
                    *(const half8*)&Lp[rbase + 2176 + LOFF + kc * 32], Ef[kc], eacc, 0, 0, 0);
            if (col < 2) {
                #pragma unroll
                for (int r = 0; r < 4; ++r)
                    out[(base + 16 + quad * 4 + r) * (TSTEPS * 2) + (TSTEPS - 1) * 2 + col] = eacc[r];
            }
        }
        if (w == 7) {   // rel_29(T3) from h_30(T3)
            f32x4 eacc = __builtin_amdgcn_mfma_f32_16x16x32_f16(
                *(const half8*)&Lp[rbase + 3 * 2176], Ef[0], einitv, 0, 0, 0);
            #pragma unroll
            for (int kc = 1; kc < 4; ++kc)
                eacc = __builtin_amdgcn_mfma_f32_16x16x32_f16(
                    *(const half8*)&Lp[rbase + 3 * 2176 + kc * 32], Ef[kc], eacc, 0, 0, 0);
            #pragma unroll
            for (int kc = 0; kc < 4; ++kc)
                eacc = __builtin_amdgcn_mfma_f32_16x16x32_f16(
                    *(const half8*)&Lp[rbase + 3 * 2176 + LOFF + kc * 32], Ef[kc], eacc, 0, 0, 0);
            if (col < 2) {
                #pragma unroll
                for (int r = 0; r < 4; ++r)
                    out[(base + 48 + quad * 4 + r) * (TSTEPS * 2) + (TSTEPS - 1) * 2 + col] = eacc[r];
            }
        }
    }
}

extern "C" void kernel_launch(void* const* d_in, const int* in_sizes, int n_in,
                              void* d_out, int out_size, void* d_ws, size_t ws_size,
                              hipStream_t stream) {
    const float* last_obs_rel = (const float*)d_in[1];
    const float* h0    = (const float*)d_in[2];
    const float* c0    = (const float*)d_in[3];
    const float* W_sp  = (const float*)d_in[4];
    const float* b_sp  = (const float*)d_in[5];
    const float* W_ih  = (const float*)d_in[6];
    const float* b_ih  = (const float*)d_in[7];
    const float* W_hh  = (const float*)d_in[8];
    const float* b_hh  = (const float*)d_in[9];
    const float* W_out = (const float*)d_in[10];
    const float* b_out = (const float*)d_in[11];
    float* out = (float*)d_out;

    const int batch = in_sizes[2] / 128;   // 65536
    lstm30_kernel<<<dim3(batch / 64), dim3(512), 0, stream>>>(
        last_obs_rel, h0, c0, W_sp, b_sp, W_ih, b_ih, W_hh, b_hh, W_out, b_out, out);
}

// Round 7
// 540.102 us; speedup vs baseline: 1.1274x; 1.1274x over previous
//
#include <hip/hip_runtime.h>

#define TSTEPS 30
#define KP2 136           // 128 h + 8 pad halfs (272B row stride); gate frags read only k<128
#define NROWS 128         // 8 tiles x 16 rows per block

#define LOG2E     1.44269504f
#define TWO_LOG2E 2.88539008f

// R9: XOR element-index bit4 with row bit3 (write-conflict spread). Kept.
#define SWZ(row, e) ((e) ^ ((((row) >> 3) & 1) << 4))

typedef _Float16 half8 __attribute__((ext_vector_type(8)));
typedef _Float16 half4 __attribute__((ext_vector_type(4)));
typedef float f32x4 __attribute__((ext_vector_type(4)));

#if __has_builtin(__builtin_amdgcn_mfma_f32_16x16x16f16)
#define XK16 1
#else
#define XK16 0
#endif

__device__ __forceinline__ float fexp2(float x) { return __builtin_amdgcn_exp2f(x); }
__device__ __forceinline__ float frcp(float x)  { return __builtin_amdgcn_rcpf(x); }
__device__ __forceinline__ float fsig_pre(float x)  { return frcp(1.0f + fexp2(-x)); }
__device__ __forceinline__ float ftanh_pre(float x) { return 1.0f - 2.0f * frcp(1.0f + fexp2(x)); }

// R14 (resubmit; R6 was a container-acquisition failure, kernel never ran):
// 8-tile round-robin, merged step-phase, barriers every OTHER phase.
// Tiles are independent batch rows; R3's every-phase barrier existed only
// because producer->consumer slack was 1 phase. With 4 groups of 2 tiles
// cycled round-robin, every cross-wave dependency has slack >= 1 barrier.
// Audited edges (re-verified r6):
//   h(kk) written iter kk-1 ph3/4 plane (kk-1)&1 -> gates read iter kk ph1/2
//   (end barrier); e-jobs tiles 4-7 read same (end barrier); e-jobs tiles 0-3
//   read h(kk+1) written ph1/2 of same iter (mid barrier). xS/lP: disjoint
//   rows or >=1 barrier in every window. kk=0/kk=30 boundaries emit rel_0..29
//   exactly once.
// Gate accs are phase-local (32 transient regs, not 64 persistent) — R2/R5
// spill scar respected: persistent ~140 regs, peak ~210 < 256 @ (512,2).
#define CELL_ROW(ACC, CC, TT, R) do {                                   \
    const float gi_ = fsig_pre(ACC[0][R]);                              \
    const float gf_ = fsig_pre(ACC[1][R]);                              \
    const float gg_ = ftanh_pre(ACC[2][R]);                             \
    const float go_ = fsig_pre(ACC[3][R]);                              \
    CC = gf_ * CC + gi_ * gg_;                                          \
    const float hv_ = go_ * ftanh_pre(TWO_LOG2E * CC);                  \
    const _Float16 hh_ = (_Float16)hv_;                                 \
    const int row_ = (TT) * 16 + quad * 4 + (R);                        \
    hP[wpl][row_][SWZ(row_, j)] = hh_;                                  \
    lP[row_][SWZ(row_, j)] = (_Float16)(hv_ - (float)hh_);              \
} while (0)

#if XK16
#define XFIN(TA, TB) do {                                               \
    const half4 xa_ = *(const half4*)&xS[TA][col][quad * 4];            \
    const half4 xb_ = *(const half4*)&xS[TB][col][quad * 4];            \
    _Pragma("unroll")                                                   \
    for (int nt = 0; nt < 4; ++nt) {                                    \
        accA[nt] = __builtin_amdgcn_mfma_f32_16x16x16f16(xa_, Wf4[nt], accA[nt], 0, 0, 0); \
        accB[nt] = __builtin_amdgcn_mfma_f32_16x16x16f16(xb_, Wf4[nt], accB[nt], 0, 0, 0); \
    }                                                                   \
} while (0)
#else
#define XFIN(TA, TB) do {                                               \
    const half8 xa_ = *(const half8*)&xS[TA][col][quad * 8];            \
    const half8 xb_ = *(const half8*)&xS[TB][col][quad * 8];            \
    _Pragma("unroll")                                                   \
    for (int nt = 0; nt < 4; ++nt) {                                    \
        accA[nt] = __builtin_amdgcn_mfma_f32_16x16x32_f16(xa_, Wf[nt][4], accA[nt], 0, 0, 0); \
        accB[nt] = __builtin_amdgcn_mfma_f32_16x16x32_f16(xb_, Wf[nt][4], accB[nt], 0, 0, 0); \
    }                                                                   \
} while (0)
#endif

// x e-job: x(KEV) = tanh(2log2e*(M.h(KEV)+mb)) via fused M = Wsp*Wout (hi-only h)
#define EJOB_X(ET, EPL) do {                                            \
    f32x4 eacc = {einit, einit, einit, einit};                          \
    _Pragma("unroll")                                                   \
    for (int kc = 0; kc < 4; ++kc) {                                    \
        const half8 aH_ = *(const half8*)&hP[EPL][(ET) * 16 + col][SWZ((ET) * 16 + col, kc * 32 + quad * 8)]; \
        eacc = __builtin_amdgcn_mfma_f32_16x16x32_f16(aH_, Ef[kc], eacc, 0, 0, 0); \
    }                                                                   \
    _Pragma("unroll")                                                   \
    for (int r = 0; r < 4; ++r)                                         \
        xS[ET][quad * 4 + r][col] = (_Float16)ftanh_pre(eacc[r]);       \
} while (0)

// rel e-job: hi+lo compensated read (output precision), direct global write
#define EJOB_REL(ET, KEV, EPL) do {                                     \
    f32x4 eacc = {einit, einit, einit, einit};                          \
    _Pragma("unroll")                                                   \
    for (int kc = 0; kc < 4; ++kc) {                                    \
        const half8 aH_ = *(const half8*)&hP[EPL][(ET) * 16 + col][SWZ((ET) * 16 + col, kc * 32 + quad * 8)]; \
        eacc = __builtin_amdgcn_mfma_f32_16x16x32_f16(aH_, Ef[kc], eacc, 0, 0, 0); \
    }                                                                   \
    _Pragma("unroll")                                                   \
    for (int kc = 0; kc < 4; ++kc) {                                    \
        const half8 aL_ = *(const half8*)&lP[(ET) * 16 + col][SWZ((ET) * 16 + col, kc * 32 + quad * 8)]; \
        eacc = __builtin_amdgcn_mfma_f32_16x16x32_f16(aL_, Ef[kc], eacc, 0, 0, 0); \
    }                                                                   \
    if (col < 2) {                                                      \
        _Pragma("unroll")                                               \
        for (int r = 0; r < 4; ++r)                                     \
            out[(base + (ET) * 16 + quad * 4 + r) * (TSTEPS * 2) + (KEV) * 2 + col] = eacc[r]; \
    }                                                                   \
} while (0)

// One phase: full step (gates+cell) for tiles TA,TB at step kk; e-jobs for
// tiles EA,EB at step KEV (data 2 phases old). E sits between gate-MFMA and
// cell so the 4-deep gate chain drains under independent work.
#define PHASE(TA, TB, EA, EB, DOE, KEV, EPL) do {                       \
    if (doStep) {                                                       \
        half8 aA[4], aB[4];                                             \
        _Pragma("unroll")                                               \
        for (int kc = 0; kc < 4; ++kc) {                                \
            aA[kc] = *(const half8*)&hP[rpl][(TA) * 16 + col][SWZ((TA) * 16 + col, kc * 32 + quad * 8)]; \
            aB[kc] = *(const half8*)&hP[rpl][(TB) * 16 + col][SWZ((TB) * 16 + col, kc * 32 + quad * 8)]; \
        }                                                               \
        _Pragma("unroll")                                               \
        for (int nt = 0; nt < 4; ++nt) {                                \
            f32x4 bv = {bias[nt], bias[nt], bias[nt], bias[nt]};        \
            accA[nt] = bv; accB[nt] = bv;                               \
        }                                                               \
        XFIN(TA, TB);                                                   \
        _Pragma("unroll")                                               \
        for (int kc = 0; kc < 4; ++kc)                                  \
            _Pragma("unroll")                                           \
            for (int nt = 0; nt < 4; ++nt) {                            \
                accA[nt] = __builtin_amdgcn_mfma_f32_16x16x32_f16(aA[kc], Wf[nt][kc], accA[nt], 0, 0, 0); \
                accB[nt] = __builtin_amdgcn_mfma_f32_16x16x32_f16(aB[kc], Wf[nt][kc], accB[nt], 0, 0, 0); \
            }                                                           \
    }                                                                   \
    if (DOE) {                                                          \
        if (w == 0 && (KEV) < TSTEPS - 1) EJOB_X(EA, EPL);              \
        if (w == 1 && (KEV) < TSTEPS - 1) EJOB_X(EB, EPL);              \
        if (w == 2) EJOB_REL(EA, KEV, EPL);                             \
        if (w == 3) EJOB_REL(EB, KEV, EPL);                             \
    }                                                                   \
    if (doStep) {                                                       \
        _Pragma("unroll")                                               \
        for (int r = 0; r < 4; ++r) {                                   \
            CELL_ROW(accA, c[TA][r], TA, r);                            \
            CELL_ROW(accB, c[TB][r], TB, r);                            \
        }                                                               \
    }                                                                   \
} while (0)

__global__ __launch_bounds__(512, 2)
void lstm30_kernel(const float* __restrict__ last_obs_rel,
                   const float* __restrict__ h0,
                   const float* __restrict__ c0,
                   const float* __restrict__ W_sp,
                   const float* __restrict__ b_sp,
                   const float* __restrict__ W_ih,
                   const float* __restrict__ b_ih,
                   const float* __restrict__ W_hh,
                   const float* __restrict__ b_hh,
                   const float* __restrict__ W_out,
                   const float* __restrict__ b_out,
                   float* __restrict__ out)
{
    __shared__ _Float16 hP[2][NROWS][KP2];   // hi plane, step-parity double-buffered
    __shared__ _Float16 lP[NROWS][KP2];      // lo plane, single (readers 2 phases behind writers, rows disjoint per phase)
#if XK16
    __shared__ _Float16 xS[8][16][20];
#else
    __shared__ _Float16 xS[8][16][32];
#endif

    const int tid  = threadIdx.x;
    const int w    = tid >> 6;
    const int L    = tid & 63;
    const int quad = L >> 4;
    const int col  = L & 15;
    const int base = blockIdx.x << 7;   // 128 rows/block

    // ---- gate B fragments: W'[k][G], G = nt*128 + 16w + col, pre-scaled (R3 form) ----
#if XK16
    half8 Wf[4][4];
    half4 Wf4[4];
#else
    half8 Wf[4][5];
#endif
    float bias[4];
    #pragma unroll
    for (int nt = 0; nt < 4; ++nt) {
        const int G = nt * 128 + w * 16 + col;
        const float gsc = (nt == 2) ? TWO_LOG2E : LOG2E;
        bias[nt] = (b_ih[G] + b_hh[G]) * gsc;
        #pragma unroll
        for (int kc = 0; kc < 4; ++kc) {
            const int k0 = kc * 32 + quad * 8;
            const float4 a = *(const float4*)&W_hh[G * 128 + k0];
            const float4 b = *(const float4*)&W_hh[G * 128 + k0 + 4];
            half8 hh;
            hh[0] = (_Float16)(a.x * gsc); hh[1] = (_Float16)(a.y * gsc);
            hh[2] = (_Float16)(a.z * gsc); hh[3] = (_Float16)(a.w * gsc);
            hh[4] = (_Float16)(b.x * gsc); hh[5] = (_Float16)(b.y * gsc);
            hh[6] = (_Float16)(b.z * gsc); hh[7] = (_Float16)(b.w * gsc);
            Wf[nt][kc] = hh;
        }
#if XK16
        {
            const float4 a = *(const float4*)&W_ih[G * 16 + quad * 4];
            half4 h4;
            h4[0] = (_Float16)(a.x * gsc); h4[1] = (_Float16)(a.y * gsc);
            h4[2] = (_Float16)(a.z * gsc); h4[3] = (_Float16)(a.w * gsc);
            Wf4[nt] = h4;
        }
#else
        {
            const int k0 = 128 + quad * 8;
            float v[8];
            if (k0 < 144) {
                const float4 a = *(const float4*)&W_ih[G * 16 + (k0 - 128)];
                const float4 b = *(const float4*)&W_ih[G * 16 + (k0 - 128) + 4];
                v[0]=a.x; v[1]=a.y; v[2]=a.z; v[3]=a.w;
                v[4]=b.x; v[5]=b.y; v[6]=b.z; v[7]=b.w;
            } else {
                #pragma unroll
                for (int jj = 0; jj < 8; ++jj) v[jj] = 0.0f;
            }
            half8 hh;
            #pragma unroll
            for (int jj = 0; jj < 8; ++jj) hh[jj] = (_Float16)(v[jj] * gsc);
            Wf[nt][4] = hh;
        }
#endif
    }

    const float ws0 = W_sp[col * 2 + 0];
    const float ws1 = W_sp[col * 2 + 1];
    const float bs  = b_sp[col];
    const float bo0 = b_out[0], bo1 = b_out[1];

    // ---- per-wave Ef variant: M-path (w0,1,4,5) or Wout-path (w2,3,6,7) ----
    half8 Ef[4];
    float einit;
    {
        const bool isM = ((w & 2) == 0);
        #pragma unroll
        for (int kc = 0; kc < 4; ++kc) {
            const int k0 = kc * 32 + quad * 8;
            const float4 a0 = *(const float4*)&W_out[k0];
            const float4 a1 = *(const float4*)&W_out[k0 + 4];
            const float4 b0 = *(const float4*)&W_out[128 + k0];
            const float4 b1 = *(const float4*)&W_out[128 + k0 + 4];
            float r0[8] = {a0.x,a0.y,a0.z,a0.w,a1.x,a1.y,a1.z,a1.w};
            float r1[8] = {b0.x,b0.y,b0.z,b0.w,b1.x,b1.y,b1.z,b1.w};
            half8 he;
            #pragma unroll
            for (int jj = 0; jj < 8; ++jj)
                he[jj] = isM ? (_Float16)((ws0 * r0[jj] + ws1 * r1[jj]) * TWO_LOG2E)
                             : (_Float16)((col == 0) ? r0[jj] : (col == 1) ? r1[jj] : 0.0f);
            Ef[kc] = he;
        }
        einit = isM ? (ws0 * bo0 + ws1 * bo1 + bs) * TWO_LOG2E
                    : ((col == 0) ? bo0 : (col == 1) ? bo1 : 0.0f);
    }

    const int j = w * 16 + col;

    float c[8][4];
    #pragma unroll
    for (int t = 0; t < 8; ++t)
        #pragma unroll
        for (int r = 0; r < 4; ++r)
            c[t][r] = c0[(base + t * 16 + quad * 4 + r) * 128 + j];

    // ---- prologue: h0 -> hP[1] hi (lo plane needs no init: rel reads only
    // cell-written lo); obs-x0 -> xS all 8 tiles ----
    for (int i = tid; i < NROWS * 32; i += 512) {   // 128 rows x 32 float4
        const int r  = i >> 5;
        const int k4 = (i & 31) * 4;
        const float4 v = *(const float4*)&h0[(base + r) * 128 + k4];
        half4 hv;
        hv[0] = (_Float16)v.x; hv[1] = (_Float16)v.y;
        hv[2] = (_Float16)v.z; hv[3] = (_Float16)v.w;
        *(half4*)&hP[1][r][SWZ(r, k4)] = hv;        // SWZ flips bit4 only: half4 stays contiguous+aligned
    }
    #pragma unroll
    for (int hh = 0; hh < 4; ++hh) {
        const int rr = (tid >> 4) + hh * 32;
        const float p0 = last_obs_rel[(base + rr) * 2 + 0];
        const float p1 = last_obs_rel[(base + rr) * 2 + 1];
        xS[rr >> 4][rr & 15][col] = (_Float16)ftanh_pre(TWO_LOG2E * (ws0 * p0 + ws1 * p1 + bs));
    }
#if !XK16
    for (int flat = tid; flat < 8 * 16 * 16; flat += 512) {
        xS[flat >> 8][(flat >> 4) & 15][16 + (flat & 15)] = (_Float16)0.0f;
    }
#endif
    __syncthreads();

    // ---- main: 31 macro-iterations x 4 phases; barrier after phases g=1 and g=3 ----
    for (int kk = 0; kk <= TSTEPS; ++kk) {
        const int wpl = kk & 1;        // cell writes h(kk+1) here
        const int rpl = wpl ^ 1;       // gates read h(kk) here (kk=0: prologue plane 1)
        const bool doStep = (kk < TSTEPS);
        const bool doE01  = (kk >= 1);         // groups 0,1 host e-jobs for step kk-1 (plane rpl)
        const bool doE23  = (kk < TSTEPS);     // groups 2,3 host e-jobs for step kk   (plane wpl)
        f32x4 accA[4], accB[4];

        PHASE(0, 1, 4, 5, doE01, kk - 1, rpl);
        PHASE(2, 3, 6, 7, doE01, kk - 1, rpl);
        __syncthreads();
        PHASE(4, 5, 0, 1, doE23, kk, wpl);
        PHASE(6, 7, 2, 3, doE23, kk, wpl);
        __syncthreads();
    }
}

extern "C" void kernel_launch(void* const* d_in, const int* in_sizes, int n_in,
                              void* d_out, int out_size, void* d_ws, size_t ws_size,
                              hipStream_t stream) {
    const float* last_obs_rel = (const float*)d_in[1];
    const float* h0    = (const float*)d_in[2];
    const float* c0    = (const float*)d_in[3];
    const float* W_sp  = (const float*)d_in[4];
    const float* b_sp  = (const float*)d_in[5];
    const float* W_ih  = (const float*)d_in[6];
    const float* b_ih  = (const float*)d_in[7];
    const float* W_hh  = (const float*)d_in[8];
    const float* b_hh  = (const float*)d_in[9];
    const float* W_out = (const float*)d_in[10];
    const float* b_out = (const float*)d_in[11];
    float* out = (float*)d_out;

    const int batch = in_sizes[2] / 128;   // 65536
    lstm30_kernel<<<dim3(batch / 128), dim3(512), 0, stream>>>(
        last_obs_rel, h0, c0, W_sp, b_sp, W_ih, b_ih, W_hh, b_hh, W_out, b_out, out);
}